// Round 1
// baseline (255.683 us; speedup 1.0000x reference)
//
#include <hip/hip_runtime.h>

// Problem constants (from reference setup_inputs):
//   out0, out1, targets: [16, 21, 256, 256] f32; out2: [16, 21] f32; output: 1 f32 scalar.
constexpr int kB = 16;
constexpr int kC = 21;
constexpr int kHW = 256 * 256;
constexpr int kPerSample = kC * kHW;           // 1376256 (divisible by 4)
constexpr int kN = kB * kPerSample;            // 22020096
constexpr int kN4 = kN / 4;                    // 5505024

// Numerically stable BCE-with-logits term: max(x,0) - x*t + log(1+exp(-|x|)).
// Fast intrinsics are fine: harness threshold is ~2.6e-2 on a ~1.3 scalar.
__device__ __forceinline__ float bce_term(float x, float t) {
    return fmaxf(x, 0.0f) - x * t + __logf(1.0f + __expf(-fabsf(x)));
}

// torch.histc semantics: bin_w = (n_classes-1)/n_classes = 20/21,
// idx = clip(floor(x / bin_w), 0, 20), out-of-range [0,20] values dropped.
__device__ __forceinline__ unsigned int histbit(float x) {
    if (!(x >= 0.0f && x <= 20.0f)) return 0u;
    int idx = (int)floorf(x * (21.0f / 20.0f));
    idx = idx < 0 ? 0 : (idx > 20 ? 20 : idx);
    return 1u << idx;
}

// Kernel 1: grid-stride float4 reduction over the 3 big arrays.
// Accumulates sum(bce(out0,t) + 0.4*bce(out1,t)) into wsum[0] (atomicAdd per block)
// and per-sample class-presence masks into masks[16] (atomicOr per block).
__global__ __launch_bounds__(256) void main_reduce(
    const float4* __restrict__ o0, const float4* __restrict__ o1,
    const float4* __restrict__ tg, float* __restrict__ wsum,
    unsigned int* __restrict__ masks)
{
    __shared__ unsigned int s_mask[kB];
    __shared__ float s_red[4];  // 4 waves per 256-thread block

    const int tid = threadIdx.x;
    if (tid < kB) s_mask[tid] = 0u;
    __syncthreads();

    float acc = 0.0f;
    const int stride = gridDim.x * blockDim.x;
    for (int i = blockIdx.x * blockDim.x + tid; i < kN4; i += stride) {
        float4 a = o0[i];
        float4 b = o1[i];
        float4 t = tg[i];

        float s0 = bce_term(a.x, t.x) + bce_term(a.y, t.y)
                 + bce_term(a.z, t.z) + bce_term(a.w, t.w);
        float s1 = bce_term(b.x, t.x) + bce_term(b.y, t.y)
                 + bce_term(b.z, t.z) + bce_term(b.w, t.w);
        acc += s0 + 0.4f * s1;

        // Class-presence bits. float4 never straddles a sample boundary
        // (kPerSample % 4 == 0). Shared mask saturates fast (targets are 0/1),
        // so the atomicOr path is cold after the first few iterations.
        unsigned int m = histbit(t.x) | histbit(t.y) | histbit(t.z) | histbit(t.w);
        int samp = (i * 4) / kPerSample;
        if (m & ~s_mask[samp]) atomicOr(&s_mask[samp], m);
    }

    // Wave64 shuffle reduction, then cross-wave via LDS, one atomicAdd/block.
    #pragma unroll
    for (int off = 32; off >= 1; off >>= 1)
        acc += __shfl_down(acc, off, 64);
    if ((tid & 63) == 0) s_red[tid >> 6] = acc;
    __syncthreads();
    if (tid == 0) {
        float s = s_red[0] + s_red[1] + s_red[2] + s_red[3];
        atomicAdd(wsum, s);
    }
    // Flush per-sample masks (after barrier: all lane contributions visible).
    if (tid < kB) {
        unsigned int m = s_mask[tid];
        if (m) atomicOr(&masks[tid], m);
    }
}

// Kernel 2: 336-element SE BCE from out2 + masks, then combine all terms.
__global__ __launch_bounds__(512) void finish_kernel(
    const float* __restrict__ out2, const unsigned int* __restrict__ masks,
    const float* __restrict__ wsum, float* __restrict__ out)
{
    __shared__ float s_red[8];
    const int tid = threadIdx.x;
    float acc = 0.0f;
    if (tid < kB * kC) {
        int b = tid / kC;
        int c = tid - b * kC;
        float t = (float)((masks[b] >> c) & 1u);
        acc = bce_term(out2[tid], t);
    }
    #pragma unroll
    for (int off = 32; off >= 1; off >>= 1)
        acc += __shfl_down(acc, off, 64);
    if ((tid & 63) == 0) s_red[tid >> 6] = acc;
    __syncthreads();
    if (tid == 0) {
        float se = 0.0f;
        #pragma unroll
        for (int w = 0; w < 8; ++w) se += s_red[w];
        // loss + 0.4*loss_aux already combined in wsum (per-element weighting).
        out[0] = wsum[0] * (1.0f / (float)kN) + 0.2f * (se / (float)(kB * kC));
    }
}

extern "C" void kernel_launch(void* const* d_in, const int* in_sizes, int n_in,
                              void* d_out, int out_size, void* d_ws, size_t ws_size,
                              hipStream_t stream) {
    const float* out0    = (const float*)d_in[0];
    const float* out1    = (const float*)d_in[1];
    const float* out2    = (const float*)d_in[2];
    const float* targets = (const float*)d_in[3];

    float*        wsum  = (float*)d_ws;
    unsigned int* masks = (unsigned int*)((char*)d_ws + 64);

    // ws is re-poisoned to 0xAA before every launch — zero our accumulators.
    hipMemsetAsync(d_ws, 0, 128, stream);

    // 2048 blocks x 256 threads: ~10.5 float4 iters/thread, 8 blocks/CU.
    main_reduce<<<2048, 256, 0, stream>>>(
        (const float4*)out0, (const float4*)out1, (const float4*)targets,
        wsum, masks);
    finish_kernel<<<1, 512, 0, stream>>>(out2, masks, wsum, (float*)d_out);
}

// Round 2
// 254.486 us; speedup vs baseline: 1.0047x; 1.0047x over previous
//
#include <hip/hip_runtime.h>

// Problem: out0, out1, targets: [16, 21, 256, 256] f32; out2: [16, 21] f32.
// Output: scalar f32 = mean(bce(out0,t)) + 0.4*mean(bce(out1,t)) + 0.2*mean(bce(out2, presence)).
constexpr int kB = 16;
constexpr int kC = 21;
constexpr int kPerSample = kC * 256 * 256;                    // 1376256
constexpr int kN = kB * kPerSample;                           // 22020096
constexpr int kF4PerSample = kPerSample / 4;                  // 344064
constexpr int kBlocksPerSample = 168;                         // 344064 / 168 = 2048 float4/block
constexpr int kF4PerBlock = kF4PerSample / kBlocksPerSample;  // 2048
constexpr int kIters = kF4PerBlock / 256;                     // 8 float4 per thread
constexpr int kGrid = kB * kBlocksPerSample;                  // 2688 blocks

// Stable BCE-with-logits term: max(x,0) - x*t + log(1+exp(-|x|)).
__device__ __forceinline__ float bce_term(float x, float t) {
    return fmaxf(x, 0.0f) - x * t + __logf(1.0f + __expf(-fabsf(x)));
}

// torch.histc semantics: bin_w = 20/21, idx = clip(floor(x/bin_w), 0, 20),
// values outside [0, 20] dropped.
__device__ __forceinline__ unsigned int histbit(float x) {
    if (!(x >= 0.0f && x <= 20.0f)) return 0u;
    int idx = (int)floorf(x * (21.0f / 20.0f));
    idx = idx < 0 ? 0 : (idx > 20 ? 20 : idx);
    return 1u << idx;
}

// Kernel 1: each block owns a contiguous 2048-float4 chunk of ONE sample.
// No LDS, no division, no atomics in the hot loop; fully-unrolled loads give
// 24 outstanding global_load_dwordx4 per wave. Per-block partial sum + class
// mask written to distinct workspace slots (no zero-init required).
__global__ __launch_bounds__(256) void main_reduce(
    const float4* __restrict__ o0, const float4* __restrict__ o1,
    const float4* __restrict__ tg, float* __restrict__ part_sum,
    unsigned int* __restrict__ part_mask)
{
    const int tid = threadIdx.x;
    const int blk = blockIdx.x;
    const int samp = blk / kBlocksPerSample;        // const per block
    const int chunk = blk - samp * kBlocksPerSample;
    const int base = samp * kF4PerSample + chunk * kF4PerBlock + tid;

    float4 a[kIters], b[kIters], t[kIters];
    #pragma unroll
    for (int k = 0; k < kIters; ++k) {
        const int idx = base + k * 256;
        a[k] = o0[idx];
        b[k] = o1[idx];
        t[k] = tg[idx];
    }

    float acc = 0.0f;
    unsigned int m = 0u;
    #pragma unroll
    for (int k = 0; k < kIters; ++k) {
        float s0 = bce_term(a[k].x, t[k].x) + bce_term(a[k].y, t[k].y)
                 + bce_term(a[k].z, t[k].z) + bce_term(a[k].w, t[k].w);
        float s1 = bce_term(b[k].x, t[k].x) + bce_term(b[k].y, t[k].y)
                 + bce_term(b[k].z, t[k].z) + bce_term(b[k].w, t[k].w);
        acc += s0 + 0.4f * s1;
        m |= histbit(t[k].x) | histbit(t[k].y) | histbit(t[k].z) | histbit(t[k].w);
    }

    // Wave64 shuffle reduction for both sum and mask, then cross-wave via LDS.
    #pragma unroll
    for (int off = 32; off >= 1; off >>= 1) {
        acc += __shfl_down(acc, off, 64);
        m |= (unsigned int)__shfl_down((int)m, off, 64);
    }
    __shared__ float s_red[4];
    __shared__ unsigned int s_m[4];
    if ((tid & 63) == 0) { s_red[tid >> 6] = acc; s_m[tid >> 6] = m; }
    __syncthreads();
    if (tid == 0) {
        part_sum[blk] = s_red[0] + s_red[1] + s_red[2] + s_red[3];
        part_mask[blk] = s_m[0] | s_m[1] | s_m[2] | s_m[3];
    }
}

// Kernel 2: reduce 2688 partials, build per-sample presence vectors,
// compute the 336-element SE BCE, combine all three loss terms.
__global__ __launch_bounds__(1024) void finish_kernel(
    const float* __restrict__ out2, const float* __restrict__ part_sum,
    const unsigned int* __restrict__ part_mask, float* __restrict__ out)
{
    __shared__ unsigned int s_mask[kB];
    __shared__ float s_red[16];
    __shared__ float s_red2[16];
    const int tid = threadIdx.x;
    if (tid < kB) s_mask[tid] = 0u;
    __syncthreads();

    float acc = 0.0f;
    for (int i = tid; i < kGrid; i += 1024) {
        acc += part_sum[i];
        unsigned int m = part_mask[i];
        int s = i / kBlocksPerSample;
        if (m & ~s_mask[s]) atomicOr(&s_mask[s], m);
    }
    #pragma unroll
    for (int off = 32; off >= 1; off >>= 1)
        acc += __shfl_down(acc, off, 64);
    if ((tid & 63) == 0) s_red[tid >> 6] = acc;
    __syncthreads();  // also orders the s_mask atomics

    float se = 0.0f;
    if (tid < kB * kC) {
        int b = tid / kC;
        int c = tid - b * kC;
        float tv = (float)((s_mask[b] >> c) & 1u);
        se = bce_term(out2[tid], tv);
    }
    #pragma unroll
    for (int off = 32; off >= 1; off >>= 1)
        se += __shfl_down(se, off, 64);
    if ((tid & 63) == 0) s_red2[tid >> 6] = se;
    __syncthreads();

    if (tid == 0) {
        float main_total = 0.0f, se_total = 0.0f;
        #pragma unroll
        for (int w = 0; w < 16; ++w) { main_total += s_red[w]; se_total += s_red2[w]; }
        out[0] = main_total * (1.0f / (float)kN)
               + 0.2f * (se_total / (float)(kB * kC));
    }
}

extern "C" void kernel_launch(void* const* d_in, const int* in_sizes, int n_in,
                              void* d_out, int out_size, void* d_ws, size_t ws_size,
                              hipStream_t stream) {
    const float* out0    = (const float*)d_in[0];
    const float* out1    = (const float*)d_in[1];
    const float* out2    = (const float*)d_in[2];
    const float* targets = (const float*)d_in[3];

    float*        part_sum  = (float*)d_ws;                       // kGrid floats
    unsigned int* part_mask = (unsigned int*)((char*)d_ws + 16384); // kGrid uints

    main_reduce<<<kGrid, 256, 0, stream>>>(
        (const float4*)out0, (const float4*)out1, (const float4*)targets,
        part_sum, part_mask);
    finish_kernel<<<1, 1024, 0, stream>>>(out2, part_sum, part_mask, (float*)d_out);
}

// Round 3
// 252.384 us; speedup vs baseline: 1.0131x; 1.0083x over previous
//
#include <hip/hip_runtime.h>

// Problem: out0, out1, targets: [16, 21, 256, 256] f32; out2: [16, 21] f32.
// Output: scalar f32 = mean(bce(out0,t)) + 0.4*mean(bce(out1,t)) + 0.2*mean(bce(out2, presence)).
constexpr int kB = 16;
constexpr int kC = 21;
constexpr int kPerSample = kC * 256 * 256;                    // 1376256
constexpr int kN = kB * kPerSample;                           // 22020096
constexpr int kF4PerSample = kPerSample / 4;                  // 344064
constexpr int kBlocksPerSample = 336;                         // 344064/336 = 1024 float4/block
constexpr int kF4PerBlock = kF4PerSample / kBlocksPerSample;  // 1024
constexpr int kIters = kF4PerBlock / 256;                     // 4 float4 per thread
constexpr int kGrid = kB * kBlocksPerSample;                  // 5376 blocks

// Stable BCE-with-logits term: max(x,0) - x*t + log(1+exp(-|x|)).
__device__ __forceinline__ float bce_term(float x, float t) {
    return fmaf(-t, x, fmaxf(x, 0.0f)) + __logf(1.0f + __expf(-fabsf(x)));
}

// torch.histc semantics: bin_w = 20/21, idx = clip(floor(x/bin_w), 0, 20),
// values outside [0, 20] dropped.
__device__ __forceinline__ unsigned int histbit(float x) {
    if (!(x >= 0.0f && x <= 20.0f)) return 0u;
    int idx = (int)floorf(x * (21.0f / 20.0f));
    idx = idx < 0 ? 0 : (idx > 20 ? 20 : idx);
    return 1u << idx;
}

// Kernel 1: each block owns a contiguous 1024-float4 chunk of ONE sample.
// All 12 dwordx4 loads are issued before any compute — pinned by
// sched_barrier(0) so the compiler cannot re-interleave them to save VGPRs
// (R2 post-mortem: it collapsed the batch to ~3 outstanding loads, VGPR=44,
// leaving the kernel MLP-bound at 2.6 TB/s). 48 payload VGPRs ≈ 60 total →
// 8 waves/SIMD; 32 waves/CU x 12 outstanding dwordx4 = ~2x the Little's-law
// requirement for 6.3 TB/s.
__global__ __launch_bounds__(256) void main_reduce(
    const float4* __restrict__ o0, const float4* __restrict__ o1,
    const float4* __restrict__ tg, float* __restrict__ part_sum,
    unsigned int* __restrict__ part_mask)
{
    const int tid = threadIdx.x;
    const int blk = blockIdx.x;
    const int samp = blk / kBlocksPerSample;        // const per block
    const int chunk = blk - samp * kBlocksPerSample;
    const int base = samp * kF4PerSample + chunk * kF4PerBlock + tid;

    float4 a[kIters], b[kIters], t[kIters];
    #pragma unroll
    for (int k = 0; k < kIters; ++k) {
        const int idx = base + k * 256;
        a[k] = o0[idx];
        b[k] = o1[idx];
        t[k] = tg[idx];
    }
    __builtin_amdgcn_sched_barrier(0);  // keep all 12 loads in flight

    float acc = 0.0f;
    unsigned int m = 0u;
    #pragma unroll
    for (int k = 0; k < kIters; ++k) {
        float s0 = bce_term(a[k].x, t[k].x) + bce_term(a[k].y, t[k].y)
                 + bce_term(a[k].z, t[k].z) + bce_term(a[k].w, t[k].w);
        float s1 = bce_term(b[k].x, t[k].x) + bce_term(b[k].y, t[k].y)
                 + bce_term(b[k].z, t[k].z) + bce_term(b[k].w, t[k].w);
        acc += s0 + 0.4f * s1;
        m |= histbit(t[k].x) | histbit(t[k].y) | histbit(t[k].z) | histbit(t[k].w);
    }

    // Wave64 shuffle reduction for both sum and mask, then cross-wave via LDS.
    #pragma unroll
    for (int off = 32; off >= 1; off >>= 1) {
        acc += __shfl_down(acc, off, 64);
        m |= (unsigned int)__shfl_down((int)m, off, 64);
    }
    __shared__ float s_red[4];
    __shared__ unsigned int s_m[4];
    if ((tid & 63) == 0) { s_red[tid >> 6] = acc; s_m[tid >> 6] = m; }
    __syncthreads();
    if (tid == 0) {
        part_sum[blk] = s_red[0] + s_red[1] + s_red[2] + s_red[3];
        part_mask[blk] = s_m[0] | s_m[1] | s_m[2] | s_m[3];
    }
}

// Kernel 2: reduce 5376 partials, build per-sample presence vectors,
// compute the 336-element SE BCE, combine all three loss terms.
__global__ __launch_bounds__(1024) void finish_kernel(
    const float* __restrict__ out2, const float* __restrict__ part_sum,
    const unsigned int* __restrict__ part_mask, float* __restrict__ out)
{
    __shared__ unsigned int s_mask[kB];
    __shared__ float s_red[16];
    __shared__ float s_red2[16];
    const int tid = threadIdx.x;
    if (tid < kB) s_mask[tid] = 0u;
    __syncthreads();

    float acc = 0.0f;
    for (int i = tid; i < kGrid; i += 1024) {
        acc += part_sum[i];
        unsigned int m = part_mask[i];
        int s = i / kBlocksPerSample;
        if (m & ~s_mask[s]) atomicOr(&s_mask[s], m);
    }
    #pragma unroll
    for (int off = 32; off >= 1; off >>= 1)
        acc += __shfl_down(acc, off, 64);
    if ((tid & 63) == 0) s_red[tid >> 6] = acc;
    __syncthreads();  // also orders the s_mask atomics

    float se = 0.0f;
    if (tid < kB * kC) {
        int b = tid / kC;
        int c = tid - b * kC;
        float tv = (float)((s_mask[b] >> c) & 1u);
        se = bce_term(out2[tid], tv);
    }
    #pragma unroll
    for (int off = 32; off >= 1; off >>= 1)
        se += __shfl_down(se, off, 64);
    if ((tid & 63) == 0) s_red2[tid >> 6] = se;
    __syncthreads();

    if (tid == 0) {
        float main_total = 0.0f, se_total = 0.0f;
        #pragma unroll
        for (int w = 0; w < 16; ++w) { main_total += s_red[w]; se_total += s_red2[w]; }
        out[0] = main_total * (1.0f / (float)kN)
               + 0.2f * (se_total / (float)(kB * kC));
    }
}

extern "C" void kernel_launch(void* const* d_in, const int* in_sizes, int n_in,
                              void* d_out, int out_size, void* d_ws, size_t ws_size,
                              hipStream_t stream) {
    const float* out0    = (const float*)d_in[0];
    const float* out1    = (const float*)d_in[1];
    const float* out2    = (const float*)d_in[2];
    const float* targets = (const float*)d_in[3];

    float*        part_sum  = (float*)d_ws;                        // kGrid floats (21.5 KB)
    unsigned int* part_mask = (unsigned int*)((char*)d_ws + 32768); // kGrid uints (21.5 KB)

    main_reduce<<<kGrid, 256, 0, stream>>>(
        (const float4*)out0, (const float4*)out1, (const float4*)targets,
        part_sum, part_mask);
    finish_kernel<<<1, 1024, 0, stream>>>(out2, part_sum, part_mask, (float*)d_out);
}